// Round 1
// baseline (1170.003 us; speedup 1.0000x reference)
//
#include <hip/hip_runtime.h>

#define T_STEPS 512
#define BATCH   1024
#define HID     128

typedef __attribute__((ext_vector_type(8))) short short8;
typedef __attribute__((ext_vector_type(4))) float f32x4;

__device__ __forceinline__ unsigned cvtpk_bf16(float lo, float hi) {
    unsigned r;
    asm("v_cvt_pk_bf16_f32 %0, %1, %2" : "=v"(r) : "v"(lo), "v"(hi));
    return r;
}

__device__ __forceinline__ float fast_sigmoid(float x) {
    // 1 / (1 + 2^(-x*log2e))
    return __builtin_amdgcn_rcpf(1.0f + __builtin_amdgcn_exp2f(-1.442695041f * x));
}
__device__ __forceinline__ float fast_tanh(float x) {
    // 1 - 2/(e^{2x}+1)
    return 1.0f - 2.0f * __builtin_amdgcn_rcpf(1.0f + __builtin_amdgcn_exp2f(2.885390082f * x));
}

__device__ __forceinline__ float gru_el(float pr, float pz, float pxn, float phn, float h) {
    float r = fast_sigmoid(pr);
    float z = fast_sigmoid(pz);
    float n = fast_tanh(pxn + r * phn);
    return n + z * (h - n);
}

__global__ __launch_bounds__(512, 2) void gru_scan(
    const float* __restrict__ x, const float* __restrict__ h0,
    const float* __restrict__ w_ih, const float* __restrict__ w_hh,
    const float* __restrict__ b_ih, const float* __restrict__ b_hh,
    const float* __restrict__ w_out, const float* __restrict__ b_out,
    float* __restrict__ out)
{
    // stride 132 breaks the 4-group (m += 4) same-bank pattern
    __shared__ float pre_r[16 * 132];
    __shared__ float pre_z[16 * 132];
    __shared__ float pre_xn[16 * 132];
    __shared__ float pre_hn[16 * 132];
    __shared__ float h32[16 * 132];
    __shared__ unsigned hbf[16 * 64];   // bf16[16][128], XOR-swizzled rows

    const int tid = threadIdx.x;
    const int w   = tid >> 6;     // wave 0..7  -> N-slice of 48 cols
    const int l   = tid & 63;
    const int lm  = l & 15;       // M index (A frags) / N index (B frags)
    const int lg  = l >> 4;       // lane group 0..3 -> K offset
    const int b0  = blockIdx.x << 4;

    // ---- load weights once into per-wave register fragments (bf16) ----
    short8 wih[3][4], whh[3][4];
    float biasX[3], biasH[3];
    #pragma unroll
    for (int f = 0; f < 3; ++f) {
        const int n = w * 48 + f * 16 + lm;      // global output column 0..383
        biasX[f] = b_ih[n];
        biasH[f] = b_hh[n];
        #pragma unroll
        for (int kf = 0; kf < 4; ++kf) {
            const int koff = kf * 32 + lg * 8;
            union { short8 s; unsigned u[4]; } p;
            {
                const float4 a = *(const float4*)(w_ih + n * HID + koff);
                const float4 b = *(const float4*)(w_ih + n * HID + koff + 4);
                p.u[0] = cvtpk_bf16(a.x, a.y); p.u[1] = cvtpk_bf16(a.z, a.w);
                p.u[2] = cvtpk_bf16(b.x, b.y); p.u[3] = cvtpk_bf16(b.z, b.w);
                wih[f][kf] = p.s;
            }
            {
                const float4 a = *(const float4*)(w_hh + n * HID + koff);
                const float4 b = *(const float4*)(w_hh + n * HID + koff + 4);
                p.u[0] = cvtpk_bf16(a.x, a.y); p.u[1] = cvtpk_bf16(a.z, a.w);
                p.u[2] = cvtpk_bf16(b.x, b.y); p.u[3] = cvtpk_bf16(b.z, b.w);
                whh[f][kf] = p.s;
            }
        }
    }

    // ---- init h (f32 copy + swizzled bf16 copy) ----
    {
        const int m  = tid >> 5;
        const int j0 = (tid & 31) << 2;
        const float4 hv = *(const float4*)(h0 + (b0 + m) * HID + j0);
        *(float4*)&h32[m * 132 + j0] = hv;
        const unsigned lo = cvtpk_bf16(hv.x, hv.y);
        const unsigned hi = cvtpk_bf16(hv.z, hv.w);
        const int bo = (j0 * 2) ^ ((m & 7) << 4);
        *(uint2*)&hbf[m * 64 + (bo >> 2)] = make_uint2(lo, hi);
    }

    // ---- prefetch x[0] into registers (A-frag layout) ----
    float4 xnA[4], xnB[4];
    {
        const float* xr = x + (size_t)(b0 + lm) * HID;
        #pragma unroll
        for (int kf = 0; kf < 4; ++kf) {
            const int koff = kf * 32 + lg * 8;
            xnA[kf] = *(const float4*)(xr + koff);
            xnB[kf] = *(const float4*)(xr + koff + 4);
        }
    }

    __syncthreads();

    for (int t = 0; t < T_STEPS; ++t) {
        // convert prefetched x -> bf16 A-frags
        short8 xa[4];
        #pragma unroll
        for (int kf = 0; kf < 4; ++kf) {
            union { short8 s; unsigned u[4]; } p;
            p.u[0] = cvtpk_bf16(xnA[kf].x, xnA[kf].y);
            p.u[1] = cvtpk_bf16(xnA[kf].z, xnA[kf].w);
            p.u[2] = cvtpk_bf16(xnB[kf].x, xnB[kf].y);
            p.u[3] = cvtpk_bf16(xnB[kf].z, xnB[kf].w);
            xa[kf] = p.s;
        }
        // prefetch x[t+1]
        {
            const int tn = (t < T_STEPS - 1) ? (t + 1) : t;
            const float* xr = x + ((size_t)tn * BATCH + b0 + lm) * HID;
            #pragma unroll
            for (int kf = 0; kf < 4; ++kf) {
                const int koff = kf * 32 + lg * 8;
                xnA[kf] = *(const float4*)(xr + koff);
                xnB[kf] = *(const float4*)(xr + koff + 4);
            }
        }
        // read h A-frags from swizzled LDS
        short8 ha[4];
        #pragma unroll
        for (int kf = 0; kf < 4; ++kf) {
            const int bo = (kf * 64 + lg * 16) ^ ((lm & 7) << 4);
            ha[kf] = *(const short8*)&hbf[lm * 64 + (bo >> 2)];
        }
        // MFMA: accX = x@Wih^T + b_ih, accH = h@Whh^T + b_hh (kept separate for n-gate)
        f32x4 accX[3], accH[3];
        #pragma unroll
        for (int f = 0; f < 3; ++f) {
            accX[f] = (f32x4){biasX[f], biasX[f], biasX[f], biasX[f]};
            accH[f] = (f32x4){biasH[f], biasH[f], biasH[f], biasH[f]};
            #pragma unroll
            for (int kf = 0; kf < 4; ++kf) {
                accX[f] = __builtin_amdgcn_mfma_f32_16x16x32_bf16(xa[kf], wih[f][kf], accX[f], 0, 0, 0);
                accH[f] = __builtin_amdgcn_mfma_f32_16x16x32_bf16(ha[kf], whh[f][kf], accH[f], 0, 0, 0);
            }
        }
        // scatter pre-activations to LDS (D layout: col=lane&15, row=lg*4+r)
        #pragma unroll
        for (int f = 0; f < 3; ++f) {
            const int n0 = w * 48 + f * 16;
            const int n  = n0 + lm;
            if (n0 < 128) {
                #pragma unroll
                for (int r = 0; r < 4; ++r)
                    pre_r[(lg * 4 + r) * 132 + n] = accX[f][r] + accH[f][r];
            } else if (n0 < 256) {
                #pragma unroll
                for (int r = 0; r < 4; ++r)
                    pre_z[(lg * 4 + r) * 132 + (n - 128)] = accX[f][r] + accH[f][r];
            } else {
                #pragma unroll
                for (int r = 0; r < 4; ++r) {
                    pre_xn[(lg * 4 + r) * 132 + (n - 256)] = accX[f][r];
                    pre_hn[(lg * 4 + r) * 132 + (n - 256)] = accH[f][r];
                }
            }
        }
        __syncthreads();
        // gates + state update (each thread owns 4 h elements)
        {
            const int m  = tid >> 5;
            const int j0 = (tid & 31) << 2;
            const float4 vr  = *(const float4*)&pre_r[m * 132 + j0];
            const float4 vz  = *(const float4*)&pre_z[m * 132 + j0];
            const float4 vxn = *(const float4*)&pre_xn[m * 132 + j0];
            const float4 vhn = *(const float4*)&pre_hn[m * 132 + j0];
            const float4 hold = *(const float4*)&h32[m * 132 + j0];
            float4 hnew;
            hnew.x = gru_el(vr.x, vz.x, vxn.x, vhn.x, hold.x);
            hnew.y = gru_el(vr.y, vz.y, vxn.y, vhn.y, hold.y);
            hnew.z = gru_el(vr.z, vz.z, vxn.z, vhn.z, hold.z);
            hnew.w = gru_el(vr.w, vz.w, vxn.w, vhn.w, hold.w);
            *(float4*)&h32[m * 132 + j0] = hnew;
            const unsigned lo = cvtpk_bf16(hnew.x, hnew.y);
            const unsigned hi = cvtpk_bf16(hnew.z, hnew.w);
            const int bo = (j0 * 2) ^ ((m & 7) << 4);
            *(uint2*)&hbf[m * 64 + (bo >> 2)] = make_uint2(lo, hi);
        }
        __syncthreads();
    }

    // ---- output projection: out[b] = h . w_out + b_out ----
    {
        const int m  = tid >> 5;
        const int j0 = (tid & 31) << 2;
        const float4 hv = *(const float4*)&h32[m * 132 + j0];
        const float4 wv = *(const float4*)(w_out + j0);
        float s = hv.x * wv.x + hv.y * wv.y + hv.z * wv.z + hv.w * wv.w;
        #pragma unroll
        for (int k = 16; k >= 1; k >>= 1) s += __shfl_xor(s, k, 32);
        if ((tid & 31) == 0) out[b0 + m] = s + b_out[0];
    }
}

extern "C" void kernel_launch(void* const* d_in, const int* in_sizes, int n_in,
                              void* d_out, int out_size, void* d_ws, size_t ws_size,
                              hipStream_t stream) {
    const float* x     = (const float*)d_in[0];
    const float* h0    = (const float*)d_in[1];
    const float* w_ih  = (const float*)d_in[2];
    const float* w_hh  = (const float*)d_in[3];
    const float* b_ih  = (const float*)d_in[4];
    const float* b_hh  = (const float*)d_in[5];
    const float* w_out = (const float*)d_in[6];
    const float* b_out = (const float*)d_in[7];
    gru_scan<<<64, 512, 0, stream>>>(x, h0, w_ih, w_hh, b_ih, b_hh, w_out, b_out, (float*)d_out);
}

// Round 2
// 1166.330 us; speedup vs baseline: 1.0031x; 1.0031x over previous
//
#include <hip/hip_runtime.h>

#define T_STEPS 512
#define BATCH   1024
#define HID     128

typedef __attribute__((ext_vector_type(8))) short short8;
typedef __attribute__((ext_vector_type(4))) float f32x4;

__device__ __forceinline__ unsigned cvtpk_bf16(float lo, float hi) {
    unsigned r;
    asm("v_cvt_pk_bf16_f32 %0, %1, %2" : "=v"(r) : "v"(lo), "v"(hi));
    return r;
}

__device__ __forceinline__ float fast_sigmoid(float x) {
    return __builtin_amdgcn_rcpf(1.0f + __builtin_amdgcn_exp2f(-1.442695041f * x));
}
__device__ __forceinline__ float fast_tanh(float x) {
    return 1.0f - 2.0f * __builtin_amdgcn_rcpf(1.0f + __builtin_amdgcn_exp2f(2.885390082f * x));
}

// Wave w owns output columns {w*16+lm, 128+w*16+lm, 256+w*16+lm} = gates r,z,n
// for the SAME 16 feature cols -> gates + h-update happen fully in registers.
// Only the bf16 (swizzled, double-buffered) copy of h crosses LDS. 1 barrier/step.
__global__ __launch_bounds__(512, 2) void gru_scan(
    const float* __restrict__ x, const float* __restrict__ h0,
    const float* __restrict__ w_ih, const float* __restrict__ w_hh,
    const float* __restrict__ b_ih, const float* __restrict__ b_hh,
    const float* __restrict__ w_out, const float* __restrict__ b_out,
    float* __restrict__ out)
{
    __shared__ unsigned hbf[2][16 * 64];   // bf16[16][128], XOR-swizzled rows, double-buffered
    __shared__ float red[16][8];

    const int tid = threadIdx.x;
    const int w   = tid >> 6;     // wave 0..7 -> feature-col block w*16..w*16+15
    const int l   = tid & 63;
    const int lm  = l & 15;       // A-frag row (batch) / B-frag col / D col
    const int lg  = l >> 4;       // lane group -> K offset / D row group
    const int b0  = blockIdx.x << 4;
    const int col = w * 16 + lm;  // this lane's feature column (D layout)

    // ---- load weights once into per-wave register fragments (bf16) ----
    // gate f in {0,1,2} = {r,z,n}; global output row n = f*128 + col
    short8 wih[3][4], whh[3][4];
    float biasX[3], biasH[3];
    #pragma unroll
    for (int f = 0; f < 3; ++f) {
        const int n = f * 128 + col;
        biasX[f] = b_ih[n];
        biasH[f] = b_hh[n];
        #pragma unroll
        for (int kf = 0; kf < 4; ++kf) {
            const int koff = kf * 32 + lg * 8;
            union { short8 s; unsigned u[4]; } p;
            {
                const float4 a = *(const float4*)(w_ih + n * HID + koff);
                const float4 b = *(const float4*)(w_ih + n * HID + koff + 4);
                p.u[0] = cvtpk_bf16(a.x, a.y); p.u[1] = cvtpk_bf16(a.z, a.w);
                p.u[2] = cvtpk_bf16(b.x, b.y); p.u[3] = cvtpk_bf16(b.z, b.w);
                wih[f][kf] = p.s;
            }
            {
                const float4 a = *(const float4*)(w_hh + n * HID + koff);
                const float4 b = *(const float4*)(w_hh + n * HID + koff + 4);
                p.u[0] = cvtpk_bf16(a.x, a.y); p.u[1] = cvtpk_bf16(a.z, a.w);
                p.u[2] = cvtpk_bf16(b.x, b.y); p.u[3] = cvtpk_bf16(b.z, b.w);
                whh[f][kf] = p.s;
            }
        }
    }

    // ---- init h: f32 in registers (this wave's tile), bf16 swizzled in LDS buf0 ----
    float hreg[4];
    #pragma unroll
    for (int r = 0; r < 4; ++r) {
        const int row = lg * 4 + r;                      // batch row within tile
        hreg[r] = h0[(size_t)(b0 + row) * HID + col];
        const unsigned p = cvtpk_bf16(hreg[r], hreg[r]);
        const int byte = (col * 2) ^ ((row & 7) << 4);
        ((short*)hbf[0])[row * 128 + (byte >> 1)] = (short)p;
    }

    // ---- prefetch x[0] into registers (A-frag layout: row lm) ----
    float4 xnA[4], xnB[4];
    {
        const float* xr = x + (size_t)(b0 + lm) * HID;
        #pragma unroll
        for (int kf = 0; kf < 4; ++kf) {
            const int koff = kf * 32 + lg * 8;
            xnA[kf] = *(const float4*)(xr + koff);
            xnB[kf] = *(const float4*)(xr + koff + 4);
        }
    }

    __syncthreads();

    for (int t = 0; t < T_STEPS; ++t) {
        // convert prefetched x -> bf16 A-frags
        short8 xa[4];
        #pragma unroll
        for (int kf = 0; kf < 4; ++kf) {
            union { short8 s; unsigned u[4]; } p;
            p.u[0] = cvtpk_bf16(xnA[kf].x, xnA[kf].y);
            p.u[1] = cvtpk_bf16(xnA[kf].z, xnA[kf].w);
            p.u[2] = cvtpk_bf16(xnB[kf].x, xnB[kf].y);
            p.u[3] = cvtpk_bf16(xnB[kf].z, xnB[kf].w);
            xa[kf] = p.s;
        }
        // prefetch x[t+1]
        {
            const int tn = (t < T_STEPS - 1) ? (t + 1) : t;
            const float* xr = x + ((size_t)tn * BATCH + b0 + lm) * HID;
            #pragma unroll
            for (int kf = 0; kf < 4; ++kf) {
                const int koff = kf * 32 + lg * 8;
                xnA[kf] = *(const float4*)(xr + koff);
                xnB[kf] = *(const float4*)(xr + koff + 4);
            }
        }
        // read h A-frags from swizzled LDS (buffer t&1)
        short8 ha[4];
        {
            const unsigned* hb = hbf[t & 1];
            #pragma unroll
            for (int kf = 0; kf < 4; ++kf) {
                const int bo = (kf * 64 + lg * 16) ^ ((lm & 7) << 4);
                ha[kf] = *(const short8*)&hb[lm * 64 + (bo >> 2)];
            }
        }
        // MFMA: accX[f] = x@Wih^T + b_ih, accH[f] = h@Whh^T + b_hh (f = r,z,n)
        f32x4 accX[3], accH[3];
        #pragma unroll
        for (int f = 0; f < 3; ++f) {
            accX[f] = (f32x4){biasX[f], biasX[f], biasX[f], biasX[f]};
            accH[f] = (f32x4){biasH[f], biasH[f], biasH[f], biasH[f]};
            #pragma unroll
            for (int kf = 0; kf < 4; ++kf) {
                accX[f] = __builtin_amdgcn_mfma_f32_16x16x32_bf16(xa[kf], wih[f][kf], accX[f], 0, 0, 0);
                accH[f] = __builtin_amdgcn_mfma_f32_16x16x32_bf16(ha[kf], whh[f][kf], accH[f], 0, 0, 0);
            }
        }
        // gates + state update fully in registers; write bf16 h to other buffer
        {
            short* hw = (short*)hbf[(t + 1) & 1];
            #pragma unroll
            for (int r = 0; r < 4; ++r) {
                const int row = lg * 4 + r;
                const float pr = accX[0][r] + accH[0][r];
                const float pz = accX[1][r] + accH[1][r];
                const float rr = fast_sigmoid(pr);
                const float zz = fast_sigmoid(pz);
                const float nn = fast_tanh(accX[2][r] + rr * accH[2][r]);
                const float hn = nn + zz * (hreg[r] - nn);
                hreg[r] = hn;
                const unsigned p = cvtpk_bf16(hn, hn);
                const int byte = (col * 2) ^ ((row & 7) << 4);
                hw[row * 128 + (byte >> 1)] = (short)p;
            }
        }
        __syncthreads();
    }

    // ---- output projection: out[b] = h . w_out + b_out ----
    {
        const float wv = w_out[col];
        float s0 = hreg[0] * wv, s1 = hreg[1] * wv, s2 = hreg[2] * wv, s3 = hreg[3] * wv;
        #pragma unroll
        for (int mask = 8; mask >= 1; mask >>= 1) {
            s0 += __shfl_xor(s0, mask);
            s1 += __shfl_xor(s1, mask);
            s2 += __shfl_xor(s2, mask);
            s3 += __shfl_xor(s3, mask);
        }
        if (lm == 0) {
            red[lg * 4 + 0][w] = s0;
            red[lg * 4 + 1][w] = s1;
            red[lg * 4 + 2][w] = s2;
            red[lg * 4 + 3][w] = s3;
        }
    }
    __syncthreads();
    if (tid < 16) {
        float acc = b_out[0];
        #pragma unroll
        for (int j = 0; j < 8; ++j) acc += red[tid][j];
        out[b0 + tid] = acc;
    }
}

extern "C" void kernel_launch(void* const* d_in, const int* in_sizes, int n_in,
                              void* d_out, int out_size, void* d_ws, size_t ws_size,
                              hipStream_t stream) {
    const float* x     = (const float*)d_in[0];
    const float* h0    = (const float*)d_in[1];
    const float* w_ih  = (const float*)d_in[2];
    const float* w_hh  = (const float*)d_in[3];
    const float* b_ih  = (const float*)d_in[4];
    const float* b_hh  = (const float*)d_in[5];
    const float* w_out = (const float*)d_in[6];
    const float* b_out = (const float*)d_in[7];
    gru_scan<<<64, 512, 0, stream>>>(x, h0, w_ih, w_hh, b_ih, b_hh, w_out, b_out, (float*)d_out);
}